// Round 5
// baseline (510.124 us; speedup 1.0000x reference)
//
#include <hip/hip_runtime.h>
#include <hip/hip_bf16.h>
#include <math.h>

#define N_NODES 50000
#define N_EDGES 800000
#define NFEAT   512
#define NHID    128
#define NCLASS  40
#define NCB      8                         // col buckets per row
#define CB_W     (N_NODES / NCB)           // 6250
#define NCNT     (N_NODES * NCB)           // 400000 (row,bucket) counters
#define SCAN_BLOCKS ((NCNT + 1023) / 1024) // 391
#define NSLICE   16                        // stats slices (contention spread)
#define SLICE_W  132                       // [0..127] colsum, [128] sumsq, pad
#define WT_BLOCKS 416                      // (65536+16384+16384+8192)/256

typedef short bf16x8 __attribute__((ext_vector_type(8)));
typedef float f32x4  __attribute__((ext_vector_type(4)));

__device__ inline float bf2f(unsigned short u) {
    union { unsigned int i; float f; } x; x.i = ((unsigned int)u) << 16; return x.f;
}

// ---------------------------------------------------------------------------
// Merged: weight transpose/convert (blocks 0..415) + edge histogram (rest)
// ---------------------------------------------------------------------------
__global__ __launch_bounds__(256) void wt_hist_kernel(const float* __restrict__ W0,
        const float* __restrict__ W1, const float* __restrict__ W2,
        const float* __restrict__ Wo, __hip_bfloat16* __restrict__ Wt0,
        __hip_bfloat16* __restrict__ Wt1, __hip_bfloat16* __restrict__ Wt2,
        __hip_bfloat16* __restrict__ Wot,
        const int* __restrict__ rows, const int* __restrict__ cols,
        int* __restrict__ cnt, int n) {
    if (blockIdx.x >= WT_BLOCKS) {
        int i = (blockIdx.x - WT_BLOCKS) * 256 + threadIdx.x;
        if (i < n) {
            int r = rows[i];
            int cb = cols[i] / CB_W;
            atomicAdd(&cnt[r * NCB + cb], 1);
        }
        return;
    }
    int i = blockIdx.x * 256 + threadIdx.x;
    if (i < 65536) {                                  // W0: [512,128] -> Wt0[n*512+k]
        int k = i >> 7, n2 = i & 127;
        Wt0[(size_t)n2 * 512 + k] = __float2bfloat16(W0[i]);
    } else if (i < 65536 + 16384) {
        int j = i - 65536; int k = j >> 7, n2 = j & 127;
        Wt1[(size_t)n2 * 128 + k] = __float2bfloat16(W1[j]);
    } else if (i < 65536 + 32768) {
        int j = i - 65536 - 16384; int k = j >> 7, n2 = j & 127;
        Wt2[(size_t)n2 * 128 + k] = __float2bfloat16(W2[j]);
    } else if (i < 65536 + 32768 + 8192) {            // W_out: [128,40] -> Wot[64,128] padded
        int j = i - 65536 - 32768; int k = j >> 6, n2 = j & 63;
        float v = (n2 < NCLASS) ? Wo[k * NCLASS + n2] : 0.f;
        Wot[(size_t)n2 * 128 + k] = __float2bfloat16(v);
    }
}

__global__ __launch_bounds__(1024) void scan_p1_kernel(const int* __restrict__ cnt,
                                                       int* __restrict__ bsum, int n) {
    int i = blockIdx.x * 1024 + threadIdx.x;
    int v = (i < n) ? cnt[i] : 0;
    __shared__ int sm[16];
    int lane = threadIdx.x & 63, w = threadIdx.x >> 6;
    #pragma unroll
    for (int off = 32; off > 0; off >>= 1) v += __shfl_xor(v, off, 64);
    if (lane == 0) sm[w] = v;
    __syncthreads();
    if (threadIdx.x == 0) {
        int s = 0;
        #pragma unroll
        for (int j = 0; j < 16; ++j) s += sm[j];
        bsum[blockIdx.x] = s;
    }
}

__global__ __launch_bounds__(512) void scan_p2_kernel(int* __restrict__ bsum, int nb) {
    __shared__ int wsum[8];
    int t = threadIdx.x;
    int lane = t & 63, w = t >> 6;
    int v = (t < nb) ? bsum[t] : 0;
    int x = v;
    #pragma unroll
    for (int off = 1; off < 64; off <<= 1) {
        int y = __shfl_up(x, off, 64);
        if (lane >= off) x += y;
    }
    if (lane == 63) wsum[w] = x;
    __syncthreads();
    int wbase = 0;
    for (int j = 0; j < w; ++j) wbase += wsum[j];
    if (t < nb) bsum[t] = wbase + x - v;   // exclusive
}

__global__ __launch_bounds__(1024) void scan_p3_kernel(const int* __restrict__ cnt,
                                                       const int* __restrict__ bsum,
                                                       int* __restrict__ bptr,
                                                       int* __restrict__ cursor, int n) {
    __shared__ int wsum[16];
    int b = blockIdx.x;
    int i = b * 1024 + threadIdx.x;
    int lane = threadIdx.x & 63, w = threadIdx.x >> 6;
    int v = (i < n) ? cnt[i] : 0;
    int x = v;
    #pragma unroll
    for (int off = 1; off < 64; off <<= 1) {
        int y = __shfl_up(x, off, 64);
        if (lane >= off) x += y;
    }
    if (lane == 63) wsum[w] = x;
    __syncthreads();
    int wbase = 0;
    for (int j = 0; j < w; ++j) wbase += wsum[j];
    int incl = bsum[b] + wbase + x;
    if (i < n) {
        bptr[i + 1] = incl;
        cursor[i] = incl - v;
    }
    if (i == 0) bptr[0] = 0;
}

// ---------------------------------------------------------------------------
// R14: scatter split out of gemm0. No LDS (full occupancy vs 5 blocks/CU
// under the GEMM's 27.6KB), single pass (edge arrays read once, not 4x),
// 3125 blocks instead of 12500. Order within a (row,bucket) range changes
// (global arrival order) — spmm accumulation is order-tolerant at bf16 eps.
// ---------------------------------------------------------------------------
__global__ __launch_bounds__(256) void scatter_kernel(
        const int* __restrict__ rows, const int* __restrict__ cols,
        const float* __restrict__ vals, int* __restrict__ cursor,
        int2* __restrict__ csr_cv, int n) {
    int i = blockIdx.x * 256 + threadIdx.x;
    if (i >= n) return;
    int r = rows[i];
    int c = cols[i];
    int pos = atomicAdd(&cursor[r * NCB + c / CB_W], 1);
    csr_cv[pos] = make_int2(c, __float_as_int(vals[i]));
}

// ---------------------------------------------------------------------------
// Layer-0 GEMM (R13 A-only pipelined staging, now standalone; block 0 zeros
// statsA slices). Measuring this alone attributes the old 80us dispatch.
// ---------------------------------------------------------------------------
template<int BM, int BN, int K>
__global__ __launch_bounds__(256, 4) void gemm0_kernel(
        const float* __restrict__ Xg, const __hip_bfloat16* __restrict__ Wt,
        __hip_bfloat16* __restrict__ Ob, float* __restrict__ stats_out, int M) {
    constexpr int BK  = 64;
    constexpr int LDK = 72;
    constexpr int WN  = BN / 64;
    __shared__ short As[BM * LDK];
    __shared__ short Bs[BN * LDK];
    int t = threadIdx.x;

    if (blockIdx.x == 0)
        for (int z = t; z < NSLICE * SLICE_W; z += 256) stats_out[z] = 0.f;
    int lane = t & 63;
    int w = t >> 6;
    int wm = w / WN, wn = w % WN;
    int row0 = blockIdx.x * BM;
    int m0 = wm * 32, n0 = wn * 64;
    int l15 = lane & 15, quad = lane >> 4;

    f32x4 acc[2][4] = {};
    float4 pa[4];          // A prefetch: BM*16/256 = 4 float4 per thread

#define G0_LOADA(k0_) do {                                                     \
    _Pragma("unroll")                                                          \
    for (int u = 0; u < 4; ++u) {                                              \
        int idx = t + u * 256; int r = idx >> 4, c = idx & 15;                 \
        pa[u] = make_float4(0.f, 0.f, 0.f, 0.f);                               \
        if (row0 + r < M)                                                      \
            pa[u] = *(const float4*)(Xg + (size_t)(row0 + r) * K + (k0_) + c * 4); \
    }                                                                          \
} while (0)

#define G0_STOREA() do {                                                       \
    _Pragma("unroll")                                                          \
    for (int u = 0; u < 4; ++u) {                                              \
        int idx = t + u * 256; int r = idx >> 4, c = idx & 15;                 \
        __hip_bfloat16 o[4] = {__float2bfloat16(pa[u].x), __float2bfloat16(pa[u].y), \
                               __float2bfloat16(pa[u].z), __float2bfloat16(pa[u].w)}; \
        *(short4*)(As + r * LDK + c * 4) = *(short4*)o;                        \
    }                                                                          \
} while (0)

    G0_LOADA(0);
    for (int k0 = 0; k0 < K; k0 += BK) {
        #pragma unroll
        for (int idx = t; idx < BN * 8; idx += 256) {   // B inline (Wt is L2-hot)
            int r = idx >> 3, c = idx & 7;
            uint4 v = *(const uint4*)(Wt + (size_t)r * K + k0 + c * 8);
            *(uint4*)(Bs + r * LDK + c * 8) = v;
        }
        G0_STOREA();
        __syncthreads();
        if (k0 + BK < K) G0_LOADA(k0 + BK);   // next-step X loads in flight
        #pragma unroll
        for (int ks = 0; ks < 2; ++ks) {
            bf16x8 af[2], bfv[4];
            #pragma unroll
            for (int mt = 0; mt < 2; ++mt)
                af[mt] = *(const bf16x8*)(As + (m0 + mt * 16 + l15) * LDK + ks * 32 + quad * 8);
            #pragma unroll
            for (int nt = 0; nt < 4; ++nt)
                bfv[nt] = *(const bf16x8*)(Bs + (n0 + nt * 16 + l15) * LDK + ks * 32 + quad * 8);
            #pragma unroll
            for (int mt = 0; mt < 2; ++mt)
                #pragma unroll
                for (int nt = 0; nt < 4; ++nt)
                    acc[mt][nt] = __builtin_amdgcn_mfma_f32_16x16x32_bf16(
                        af[mt], bfv[nt], acc[mt][nt], 0, 0, 0);
        }
        __syncthreads();
    }
#undef G0_LOADA
#undef G0_STOREA
    #pragma unroll
    for (int mt = 0; mt < 2; ++mt) {
        #pragma unroll
        for (int reg = 0; reg < 4; ++reg) {
            int row = row0 + m0 + mt * 16 + quad * 4 + reg;
            if (row < M) {
                #pragma unroll
                for (int nt = 0; nt < 4; ++nt)
                    Ob[(size_t)row * BN + n0 + nt * 16 + l15] =
                        __float2bfloat16(acc[mt][nt][reg]);
            }
        }
    }
}

// ---------------------------------------------------------------------------
// Fused PN+GEMM (R13: A-only pipeline): k0=0 Bm/Xb loads issued BEFORE the
// stats prologue (hides slice-reduce under HBM latency); per-step A loads for
// k+1 issued after the first barrier of step k. Wt staged inline (L2-hot).
// ---------------------------------------------------------------------------
template<int BM, int BN, bool ADD_RESID, bool WRITE_X>
__global__ __launch_bounds__(256, 4) void mfma_gemm_pn(const __hip_bfloat16* __restrict__ Bm,
                                                    __hip_bfloat16* __restrict__ Xb,
                                                    const float* __restrict__ stats_in,
                                                    float* __restrict__ stats_out,
                                                    const __hip_bfloat16* __restrict__ Wt,
                                                    __hip_bfloat16* __restrict__ Ob, int M) {
    constexpr int K = 128, BK = 64, LDK = 72;
    constexpr int WN = BN / 64;
    constexpr int NA = BM * 8 / 256;   // A-stage uint4 per thread (2 or 4)
    __shared__ short As[BM * LDK];
    __shared__ short Bs[BN * LDK];
    __shared__ float smu[128];
    __shared__ float sred[128];
    __shared__ float ssq16[NSLICE];
    __shared__ float sscale;
    int t = threadIdx.x;
    int row0 = blockIdx.x * BM;

    uint4 pbm[NA], pxo[NA];

#define PN_LOADA(k0_) do {                                                     \
    _Pragma("unroll")                                                          \
    for (int u = 0; u < NA; ++u) {                                             \
        int idx = t + u * 256; int r = idx >> 3, c = idx & 7;                  \
        int gr = row0 + r;                                                     \
        bool ok = gr < M;                                                      \
        pbm[u] = make_uint4(0u, 0u, 0u, 0u);                                   \
        if (ok) pbm[u] = *(const uint4*)(Bm + (size_t)gr * 128 + (k0_) + c * 8); \
        if (ADD_RESID) {                                                       \
            pxo[u] = make_uint4(0u, 0u, 0u, 0u);                               \
            if (ok) pxo[u] = *(const uint4*)(Xb + (size_t)gr * 128 + (k0_) + c * 8); \
        }                                                                      \
    }                                                                          \
} while (0)

#define PN_STOREA(k0_) do {                                                    \
    _Pragma("unroll")                                                          \
    for (int u = 0; u < NA; ++u) {                                             \
        int idx = t + u * 256; int r = idx >> 3, c = idx & 7;                  \
        int gr = row0 + r; int k = (k0_) + c * 8;                              \
        unsigned short* bu = (unsigned short*)&pbm[u];                         \
        unsigned short* xu = (unsigned short*)&pxo[u];                         \
        __hip_bfloat16 o[8];                                                   \
        _Pragma("unroll")                                                      \
        for (int j = 0; j < 8; ++j) {                                          \
            float v = fmaxf((bf2f(bu[j]) - smu[k + j]) * sc, 0.f);             \
            if (ADD_RESID) v += bf2f(xu[j]);                                   \
            o[j] = __float2bfloat16(v);                                        \
        }                                                                      \
        *(uint4*)(As + r * LDK + c * 8) = *(uint4*)o;                          \
        if (WRITE_X && gr < M) *(uint4*)(Xb + (size_t)gr * 128 + k) = *(uint4*)o; \
    }                                                                          \
} while (0)

    PN_LOADA(0);   // in flight across the stats prologue

    if (stats_out && blockIdx.x == 0)
        for (int z = t; z < NSLICE * SLICE_W; z += 256) stats_out[z] = 0.f;
    if (t < NSLICE) ssq16[t] = stats_in[t * SLICE_W + 128];
    if (t < 128) {
        float cs = 0.f;
        #pragma unroll
        for (int s = 0; s < NSLICE; ++s) cs += stats_in[s * SLICE_W + t];
        float mu = cs * (1.0f / N_NODES);
        smu[t] = mu;
        sred[t] = mu * mu;
    }
    __syncthreads();
    for (int off = 64; off > 0; off >>= 1) {
        if (t < off) sred[t] += sred[t + off];
        __syncthreads();
    }
    if (t == 0) {
        float sq = 0.f;
        #pragma unroll
        for (int s = 0; s < NSLICE; ++s) sq += ssq16[s];
        float ms = sq * (1.0f / N_NODES) - sred[0];
        sscale = 1.0f / sqrtf(1e-6f + ms);   // PN_SCALE = 1
    }
    __syncthreads();
    float sc = sscale;

    int lane = t & 63;
    int w = t >> 6;
    int wm = w / WN, wn = w % WN;
    int m0 = wm * 32, n0 = wn * 64;
    int l15 = lane & 15, quad = lane >> 4;

    f32x4 acc[2][4] = {};

    for (int k0 = 0; k0 < K; k0 += BK) {
        #pragma unroll
        for (int idx = t; idx < BN * 8; idx += 256) {   // B inline (Wt is L2-hot)
            int r = idx >> 3, c = idx & 7;
            uint4 v = *(const uint4*)(Wt + (size_t)r * K + k0 + c * 8);
            *(uint4*)(Bs + r * LDK + c * 8) = v;
        }
        PN_STOREA(k0);
        __syncthreads();
        if (k0 + BK < K) PN_LOADA(k0 + BK);   // next-step A loads in flight
        #pragma unroll
        for (int ks = 0; ks < 2; ++ks) {
            bf16x8 af[2], bfv[4];
            #pragma unroll
            for (int mt = 0; mt < 2; ++mt)
                af[mt] = *(const bf16x8*)(As + (m0 + mt * 16 + l15) * LDK + ks * 32 + quad * 8);
            #pragma unroll
            for (int nt = 0; nt < 4; ++nt)
                bfv[nt] = *(const bf16x8*)(Bs + (n0 + nt * 16 + l15) * LDK + ks * 32 + quad * 8);
            #pragma unroll
            for (int mt = 0; mt < 2; ++mt)
                #pragma unroll
                for (int nt = 0; nt < 4; ++nt)
                    acc[mt][nt] = __builtin_amdgcn_mfma_f32_16x16x32_bf16(
                        af[mt], bfv[nt], acc[mt][nt], 0, 0, 0);
        }
        __syncthreads();
    }
#undef PN_LOADA
#undef PN_STOREA
    #pragma unroll
    for (int mt = 0; mt < 2; ++mt) {
        #pragma unroll
        for (int reg = 0; reg < 4; ++reg) {
            int row = row0 + m0 + mt * 16 + quad * 4 + reg;
            if (row < M) {
                #pragma unroll
                for (int nt = 0; nt < 4; ++nt)
                    Ob[(size_t)row * BN + n0 + nt * 16 + l15] =
                        __float2bfloat16(acc[mt][nt][reg]);
            }
        }
    }
}

// ---------------------------------------------------------------------------
// CSR SpMM, 128 feats (R11 body: one wave per row as 4 groups x 16 lanes,
// 16B/lane dwordx4 gathers, 16-edge main step. ALL hot-loop state in NAMED
// scalars. cv loads WAVE-UNIFORM (s_loads); group selects via 2-level cndmask.
// Fused PN stats epilogue: block LDS reduce -> 129 atomics into 1 of 16 slices.
// ---------------------------------------------------------------------------
#define SEL4(ca, cb, cc, cd, kk, vv) do {                                     \
    int kx_ = g1 ? (cb).x : (ca).x; int vx_ = g1 ? (cb).y : (ca).y;           \
    int ky_ = g1 ? (cd).x : (cc).x; int vy_ = g1 ? (cd).y : (cc).y;           \
    kk = g2 ? ky_ : kx_; vv = __int_as_float(g2 ? vy_ : vx_);                 \
} while (0)

#define FMA8(vv, hvv) do {                                                    \
    const unsigned short* hu_ = (const unsigned short*)&(hvv);                \
    acc0[0] = fmaf((vv), bf2f(hu_[0]), acc0[0]);                              \
    acc0[1] = fmaf((vv), bf2f(hu_[1]), acc0[1]);                              \
    acc0[2] = fmaf((vv), bf2f(hu_[2]), acc0[2]);                              \
    acc0[3] = fmaf((vv), bf2f(hu_[3]), acc0[3]);                              \
    acc1[0] = fmaf((vv), bf2f(hu_[4]), acc1[0]);                              \
    acc1[1] = fmaf((vv), bf2f(hu_[5]), acc1[1]);                              \
    acc1[2] = fmaf((vv), bf2f(hu_[6]), acc1[2]);                              \
    acc1[3] = fmaf((vv), bf2f(hu_[7]), acc1[3]);                              \
} while (0)

#define GATH(kk) (*(const uint4*)(Hu + (size_t)(kk) * 128 + sub * 8))

__global__ __launch_bounds__(256) void spmm_bf16_kernel(const __hip_bfloat16* __restrict__ H,
                                                        const int* __restrict__ bptr,
                                                        const int2* __restrict__ cv,
                                                        const float* __restrict__ bias,
                                                        __hip_bfloat16* __restrict__ Bm,
                                                        float* __restrict__ stats,
                                                        int nrows) {
    __shared__ float sm[129];
    int t = threadIdx.x;
    if (t < 129) sm[t] = 0.f;
    __syncthreads();
    int wid = (int)((blockIdx.x * blockDim.x + t) >> 6);
    wid = __builtin_amdgcn_readfirstlane(wid);
    int lane = t & 63;
    int g = lane >> 4;                  // edge group 0..3
    int sub = lane & 15;                // feats [8*sub .. 8*sub+7]
    bool g1 = (lane & 16) != 0;         // g&1
    bool g2 = (lane & 32) != 0;         // g&2
    const unsigned short* Hu = (const unsigned short*)H;   // row stride 128 ushort
    f32x4 acc0 = {0.f, 0.f, 0.f, 0.f};
    f32x4 acc1 = {0.f, 0.f, 0.f, 0.f};
    if (wid < nrows) {
        int s = bptr[wid * NCB];
        int e = bptr[wid * NCB + NCB];
        int i = s;
        for (; i + 15 < e; i += 16) {   // 16 edges: group g takes i+4j+g, j=0..3
            int2 c0  = cv[i + 0],  c1  = cv[i + 1],  c2  = cv[i + 2],  c3  = cv[i + 3];
            int2 c4  = cv[i + 4],  c5  = cv[i + 5],  c6  = cv[i + 6],  c7  = cv[i + 7];
            int2 c8  = cv[i + 8],  c9  = cv[i + 9],  c10 = cv[i + 10], c11 = cv[i + 11];
            int2 c12 = cv[i + 12], c13 = cv[i + 13], c14 = cv[i + 14], c15 = cv[i + 15];
            int k0, k1, k2, k3; float v0, v1, v2, v3;
            SEL4(c0,  c1,  c2,  c3,  k0, v0);
            SEL4(c4,  c5,  c6,  c7,  k1, v1);
            SEL4(c8,  c9,  c10, c11, k2, v2);
            SEL4(c12, c13, c14, c15, k3, v3);
            uint4 h0 = GATH(k0);
            uint4 h1 = GATH(k1);
            uint4 h2 = GATH(k2);
            uint4 h3 = GATH(k3);
            FMA8(v0, h0);
            FMA8(v1, h1);
            FMA8(v2, h2);
            FMA8(v3, h3);
        }
        if (i + 7 < e) {                // 8 edges: group g takes i+4j+g, j=0..1
            int2 c0 = cv[i + 0], c1 = cv[i + 1], c2 = cv[i + 2], c3 = cv[i + 3];
            int2 c4 = cv[i + 4], c5 = cv[i + 5], c6 = cv[i + 6], c7 = cv[i + 7];
            int k0, k1; float v0, v1;
            SEL4(c0, c1, c2, c3, k0, v0);
            SEL4(c4, c5, c6, c7, k1, v1);
            uint4 h0 = GATH(k0);
            uint4 h1 = GATH(k1);
            FMA8(v0, h0);
            FMA8(v1, h1);
            i += 8;
        }
        if (i + 3 < e) {                // 4 edges: group g takes i+g
            int2 c0 = cv[i + 0], c1 = cv[i + 1], c2 = cv[i + 2], c3 = cv[i + 3];
            int k0; float v0;
            SEL4(c0, c1, c2, c3, k0, v0);
            uint4 h0 = GATH(k0);
            FMA8(v0, h0);
            i += 4;
        }
        int rr = e - i;                 // 0..3 partial: groups g<rr, one v-load
        if (g < rr) {
            int2 cc = cv[i + g];
            float v0 = __int_as_float(cc.y);
            uint4 h0 = GATH(cc.x);
            FMA8(v0, h0);
        }
    }
    // combine the 4 edge groups
    #pragma unroll
    for (int q = 0; q < 4; ++q) {
        acc0[q] += __shfl_xor(acc0[q], 16);
        acc0[q] += __shfl_xor(acc0[q], 32);
        acc1[q] += __shfl_xor(acc1[q], 16);
        acc1[q] += __shfl_xor(acc1[q], 32);
    }
    if (wid < nrows && lane < 16) {
        float4 ba = *(const float4*)(bias + 8 * sub);
        float4 bb = *(const float4*)(bias + 8 * sub + 4);
        float v0 = acc0[0] + ba.x, v1 = acc0[1] + ba.y;
        float v2 = acc0[2] + ba.z, v3 = acc0[3] + ba.w;
        float v4 = acc1[0] + bb.x, v5 = acc1[1] + bb.y;
        float v6 = acc1[2] + bb.z, v7 = acc1[3] + bb.w;
        __hip_bfloat16 o[8] = {__float2bfloat16(v0), __float2bfloat16(v1),
                               __float2bfloat16(v2), __float2bfloat16(v3),
                               __float2bfloat16(v4), __float2bfloat16(v5),
                               __float2bfloat16(v6), __float2bfloat16(v7)};
        *(uint4*)(Bm + (size_t)wid * 128 + 8 * sub) = *(uint4*)o;
        // PN stats: lane owns cols 8sub..8sub+7 exclusively within its wave
        atomicAdd(&sm[8 * sub + 0], v0);
        atomicAdd(&sm[8 * sub + 1], v1);
        atomicAdd(&sm[8 * sub + 2], v2);
        atomicAdd(&sm[8 * sub + 3], v3);
        atomicAdd(&sm[8 * sub + 4], v4);
        atomicAdd(&sm[8 * sub + 5], v5);
        atomicAdd(&sm[8 * sub + 6], v6);
        atomicAdd(&sm[8 * sub + 7], v7);
        float sq = v0 * v0 + v1 * v1 + v2 * v2 + v3 * v3
                 + v4 * v4 + v5 * v5 + v6 * v6 + v7 * v7;
        #pragma unroll
        for (int off = 8; off > 0; off >>= 1) sq += __shfl_down(sq, off, 16);
        if (sub == 0) atomicAdd(&sm[128], sq);
    }
    __syncthreads();
    if (t < 129)
        atomicAdd(&stats[(blockIdx.x & (NSLICE - 1)) * SLICE_W + t], sm[t]);
}

// ---------------------------------------------------------------------------
// Final SpMM, 64-wide G (cols 40..63 zero) — R8 body (wave-uniform cv loads)
// ---------------------------------------------------------------------------
__global__ __launch_bounds__(256) void spmm_out_kernel(const __hip_bfloat16* __restrict__ G,
                                                       const int* __restrict__ bptr,
                                                       const int2* __restrict__ cv,
                                                       const float* __restrict__ bias,
                                                       float* __restrict__ out, int nrows) {
    int wid = (int)((blockIdx.x * blockDim.x + threadIdx.x) >> 6);
    wid = __builtin_amdgcn_readfirstlane(wid);
    int lane = threadIdx.x & 63;
    int h = lane >> 5;
    int sub = lane & 31;                    // feats {2sub, 2sub+1}
    if (wid >= nrows) return;
    int s = bptr[wid * NCB];
    int e = bptr[wid * NCB + NCB];
    const __hip_bfloat162* G2 = (const __hip_bfloat162*)G;   // row stride 32
    float a0 = 0.f, a1 = 0.f;
    int i = s;
    for (; i + 7 < e; i += 8) {
        int2 c0 = cv[i],     c1 = cv[i + 1], c2 = cv[i + 2], c3 = cv[i + 3];
        int2 c4 = cv[i + 4], c5 = cv[i + 5], c6 = cv[i + 6], c7 = cv[i + 7];
        int   ka = h ? c4.x : c0.x;  float va = __int_as_float(h ? c4.y : c0.y);
        int   kb = h ? c5.x : c1.x;  float vb = __int_as_float(h ? c5.y : c1.y);
        int   kc = h ? c6.x : c2.x;  float vc = __int_as_float(h ? c6.y : c2.y);
        int   kd = h ? c7.x : c3.x;  float vd = __int_as_float(h ? c7.y : c3.y);
        __hip_bfloat162 ga = G2[(size_t)ka * 32 + sub];
        __hip_bfloat162 gb = G2[(size_t)kb * 32 + sub];
        __hip_bfloat162 gc = G2[(size_t)kc * 32 + sub];
        __hip_bfloat162 gd = G2[(size_t)kd * 32 + sub];
        a0 = fmaf(va, __bfloat162float(ga.x), a0); a1 = fmaf(va, __bfloat162float(ga.y), a1);
        a0 = fmaf(vb, __bfloat162float(gb.x), a0); a1 = fmaf(vb, __bfloat162float(gb.y), a1);
        a0 = fmaf(vc, __bfloat162float(gc.x), a0); a1 = fmaf(vc, __bfloat162float(gc.y), a1);
        a0 = fmaf(vd, __bfloat162float(gd.x), a0); a1 = fmaf(vd, __bfloat162float(gd.y), a1);
    }
    for (; i + 3 < e; i += 4) {
        int2 c0 = cv[i], c1 = cv[i + 1], c2 = cv[i + 2], c3 = cv[i + 3];
        int   ka = h ? c2.x : c0.x;  float va = __int_as_float(h ? c2.y : c0.y);
        int   kb = h ? c3.x : c1.x;  float vb = __int_as_float(h ? c3.y : c1.y);
        __hip_bfloat162 ga = G2[(size_t)ka * 32 + sub];
        __hip_bfloat162 gb = G2[(size_t)kb * 32 + sub];
        a0 = fmaf(va, __bfloat162float(ga.x), a0); a1 = fmaf(va, __bfloat162float(ga.y), a1);
        a0 = fmaf(vb, __bfloat162float(gb.x), a0); a1 = fmaf(vb, __bfloat162float(gb.y), a1);
    }
    for (; i < e; ++i) {
        int2 c = cv[i];
        if (h == 0) {
            float v = __int_as_float(c.y);
            __hip_bfloat162 g = G2[(size_t)c.x * 32 + sub];
            a0 = fmaf(v, __bfloat162float(g.x), a0);
            a1 = fmaf(v, __bfloat162float(g.y), a1);
        }
    }
    a0 += __shfl_xor(a0, 32);
    a1 += __shfl_xor(a1, 32);
    if (h == 0 && sub < NCLASS / 2) {
        float2 b2 = *(const float2*)(bias + 2 * sub);
        float2 o = make_float2(a0 + b2.x, a1 + b2.y);
        *(float2*)(out + (size_t)wid * NCLASS + 2 * sub) = o;
    }
}

// ---------------------------------------------------------------------------
extern "C" void kernel_launch(void* const* d_in, const int* in_sizes, int n_in,
                              void* d_out, int out_size, void* d_ws, size_t ws_size,
                              hipStream_t stream) {
    const float* x        = (const float*)d_in[0];
    const int*   edge_row = (const int*)  d_in[1];
    const int*   edge_col = (const int*)  d_in[2];
    const float* edge_val = (const float*)d_in[3];
    const float* W0 = (const float*)d_in[4];
    const float* b0 = (const float*)d_in[5];
    const float* W1 = (const float*)d_in[6];
    const float* b1 = (const float*)d_in[7];
    const float* W2 = (const float*)d_in[8];
    const float* b2 = (const float*)d_in[9];
    const float* W_out = (const float*)d_in[10];
    const float* b_out = (const float*)d_in[11];
    float* out = (float*)d_out;

    const size_t NH = (size_t)N_NODES * NHID;   // 6,400,000

    char* p = (char*)d_ws;
    __hip_bfloat16* Xb   = (__hip_bfloat16*)p;  p += NH * 2;
    __hip_bfloat16* A_bf = (__hip_bfloat16*)p;  p += NH * 2;
    __hip_bfloat16* Bm   = (__hip_bfloat16*)p;  p += NH * 2;
    __hip_bfloat16* Wt0 = (__hip_bfloat16*)p;   p += (size_t)128 * 512 * 2;
    __hip_bfloat16* Wt1 = (__hip_bfloat16*)p;   p += (size_t)128 * 128 * 2;
    __hip_bfloat16* Wt2 = (__hip_bfloat16*)p;   p += (size_t)128 * 128 * 2;
    __hip_bfloat16* Wot = (__hip_bfloat16*)p;   p += (size_t)64 * 128 * 2;
    float* statsA   = (float*)p;                p += (size_t)NSLICE * SLICE_W * 4;
    float* statsB   = (float*)p;                p += (size_t)NSLICE * SLICE_W * 4;
    int* cnt      = (int*)p;                    p += (size_t)NCNT * 4;
    int* bptr     = (int*)p;                    p += (size_t)(NCNT + 1) * 4 + 4; // int2 align
    int* cursor   = (int*)p;                    p += (size_t)NCNT * 4;
    int* bsum     = (int*)p;                    p += (size_t)SCAN_BLOCKS * 4 + 4;
    int2* csr_cv  = (int2*)p;                   p += (size_t)N_EDGES * 8;

    const int EB = (N_EDGES + 255) / 256;         // 3125 blocks
    const int SPMM_GRID = (N_NODES + 3) / 4;      // 12500 (4 waves/block)
    const int GEMM0_BLOCKS = (N_NODES + 63) / 64; // 782

    // --- CSR build + weight conversion (merged/overlapped) ---
    hipMemsetAsync(cnt, 0, NCNT * sizeof(int), stream);
    wt_hist_kernel<<<WT_BLOCKS + EB, 256, 0, stream>>>(
        W0, W1, W2, W_out, Wt0, Wt1, Wt2, Wot, edge_row, edge_col, cnt, N_EDGES);
    scan_p1_kernel<<<SCAN_BLOCKS, 1024, 0, stream>>>(cnt, bsum, NCNT);
    scan_p2_kernel<<<1, 512, 0, stream>>>(bsum, SCAN_BLOCKS);
    scan_p3_kernel<<<SCAN_BLOCKS, 1024, 0, stream>>>(cnt, bsum, bptr, cursor, NCNT);

    // --- scatter (single-pass, LDS-free) then layer-0 GEMM (zeros statsA) ---
    scatter_kernel<<<EB, 256, 0, stream>>>(edge_row, edge_col, edge_val,
                                           cursor, csr_cv, N_EDGES);
    gemm0_kernel<64, 128, 512><<<GEMM0_BLOCKS, 256, 0, stream>>>(
        x, Wt0, A_bf, statsA, N_NODES);
    spmm_bf16_kernel<<<SPMM_GRID, 256, 0, stream>>>(A_bf, bptr, csr_cv, b0, Bm,
                                                    statsA, N_NODES);

    // --- layer 1: PN(statsA)+GEMM (writes Xb=x1, zeros statsB) -> SpMM(statsB)
    mfma_gemm_pn<64, 128, false, true><<<GEMM0_BLOCKS, 256, 0, stream>>>(
        Bm, Xb, statsA, statsB, Wt1, A_bf, N_NODES);
    spmm_bf16_kernel<<<SPMM_GRID, 256, 0, stream>>>(A_bf, bptr, csr_cv, b1, Bm,
                                                    statsB, N_NODES);

    // --- layer 2: PN(statsB)+resid+GEMM (Xb=x2, zeros statsA) -> SpMM(statsA)
    mfma_gemm_pn<64, 128, true, true><<<GEMM0_BLOCKS, 256, 0, stream>>>(
        Bm, Xb, statsB, statsA, Wt2, A_bf, N_NODES);
    spmm_bf16_kernel<<<SPMM_GRID, 256, 0, stream>>>(A_bf, bptr, csr_cv, b2, Bm,
                                                    statsA, N_NODES);

    // --- head: PN(statsA)+resid(x2), x3 never materialized; Gp = x3 @ Wot^T ---
    mfma_gemm_pn<128, 64, true, false><<<(N_NODES + 127) / 128, 256, 0, stream>>>(
        Bm, Xb, statsA, nullptr, Wot, A_bf, N_NODES);
    spmm_out_kernel<<<(N_NODES + 3) / 4, 256, 0, stream>>>(A_bf, bptr, csr_cv, b_out,
                                                           out, N_NODES);
}

// Round 7
// 481.625 us; speedup vs baseline: 1.0592x; 1.0592x over previous
//
#include <hip/hip_runtime.h>
#include <hip/hip_bf16.h>
#include <math.h>

#define N_NODES 50000
#define N_EDGES 800000
#define NFEAT   512
#define NHID    128
#define NCLASS  40
#define NCB      8                         // col buckets per row
#define CB_W     (N_NODES / NCB)           // 6250
#define NCNT     (N_NODES * NCB)           // 400000 (row,bucket) counters
#define SCAN_BLOCKS ((NCNT + 1023) / 1024) // 391
#define NSLICE   16                        // stats slices (contention spread)
#define SLICE_W  132                       // [0..127] colsum, [128] sumsq, pad
#define WT_BLOCKS 416                      // (65536+16384+16384+8192)/256

typedef short bf16x8 __attribute__((ext_vector_type(8)));
typedef float f32x4  __attribute__((ext_vector_type(4)));

__device__ inline float bf2f(unsigned short u) {
    union { unsigned int i; float f; } x; x.i = ((unsigned int)u) << 16; return x.f;
}

// ---------------------------------------------------------------------------
// Merged: weight transpose/convert (blocks 0..415) + edge histogram (rest)
// ---------------------------------------------------------------------------
__global__ __launch_bounds__(256) void wt_hist_kernel(const float* __restrict__ W0,
        const float* __restrict__ W1, const float* __restrict__ W2,
        const float* __restrict__ Wo, __hip_bfloat16* __restrict__ Wt0,
        __hip_bfloat16* __restrict__ Wt1, __hip_bfloat16* __restrict__ Wt2,
        __hip_bfloat16* __restrict__ Wot,
        const int* __restrict__ rows, const int* __restrict__ cols,
        int* __restrict__ cnt, int n) {
    if (blockIdx.x >= WT_BLOCKS) {
        int i = (blockIdx.x - WT_BLOCKS) * 256 + threadIdx.x;
        if (i < n) {
            int r = rows[i];
            int cb = cols[i] / CB_W;
            atomicAdd(&cnt[r * NCB + cb], 1);
        }
        return;
    }
    int i = blockIdx.x * 256 + threadIdx.x;
    if (i < 65536) {                                  // W0: [512,128] -> Wt0[n*512+k]
        int k = i >> 7, n2 = i & 127;
        Wt0[(size_t)n2 * 512 + k] = __float2bfloat16(W0[i]);
    } else if (i < 65536 + 16384) {
        int j = i - 65536; int k = j >> 7, n2 = j & 127;
        Wt1[(size_t)n2 * 128 + k] = __float2bfloat16(W1[j]);
    } else if (i < 65536 + 32768) {
        int j = i - 65536 - 16384; int k = j >> 7, n2 = j & 127;
        Wt2[(size_t)n2 * 128 + k] = __float2bfloat16(W2[j]);
    } else if (i < 65536 + 32768 + 8192) {            // W_out: [128,40] -> Wot[64,128] padded
        int j = i - 65536 - 32768; int k = j >> 6, n2 = j & 63;
        float v = (n2 < NCLASS) ? Wo[k * NCLASS + n2] : 0.f;
        Wot[(size_t)n2 * 128 + k] = __float2bfloat16(v);
    }
}

__global__ __launch_bounds__(1024) void scan_p1_kernel(const int* __restrict__ cnt,
                                                       int* __restrict__ bsum, int n) {
    int i = blockIdx.x * 1024 + threadIdx.x;
    int v = (i < n) ? cnt[i] : 0;
    __shared__ int sm[16];
    int lane = threadIdx.x & 63, w = threadIdx.x >> 6;
    #pragma unroll
    for (int off = 32; off > 0; off >>= 1) v += __shfl_xor(v, off, 64);
    if (lane == 0) sm[w] = v;
    __syncthreads();
    if (threadIdx.x == 0) {
        int s = 0;
        #pragma unroll
        for (int j = 0; j < 16; ++j) s += sm[j];
        bsum[blockIdx.x] = s;
    }
}

__global__ __launch_bounds__(512) void scan_p2_kernel(int* __restrict__ bsum, int nb) {
    __shared__ int wsum[8];
    int t = threadIdx.x;
    int lane = t & 63, w = t >> 6;
    int v = (t < nb) ? bsum[t] : 0;
    int x = v;
    #pragma unroll
    for (int off = 1; off < 64; off <<= 1) {
        int y = __shfl_up(x, off, 64);
        if (lane >= off) x += y;
    }
    if (lane == 63) wsum[w] = x;
    __syncthreads();
    int wbase = 0;
    for (int j = 0; j < w; ++j) wbase += wsum[j];
    if (t < nb) bsum[t] = wbase + x - v;   // exclusive
}

__global__ __launch_bounds__(1024) void scan_p3_kernel(const int* __restrict__ cnt,
                                                       const int* __restrict__ bsum,
                                                       int* __restrict__ bptr,
                                                       int* __restrict__ cursor, int n) {
    __shared__ int wsum[16];
    int b = blockIdx.x;
    int i = b * 1024 + threadIdx.x;
    int lane = threadIdx.x & 63, w = threadIdx.x >> 6;
    int v = (i < n) ? cnt[i] : 0;
    int x = v;
    #pragma unroll
    for (int off = 1; off < 64; off <<= 1) {
        int y = __shfl_up(x, off, 64);
        if (lane >= off) x += y;
    }
    if (lane == 63) wsum[w] = x;
    __syncthreads();
    int wbase = 0;
    for (int j = 0; j < w; ++j) wbase += wsum[j];
    int incl = bsum[b] + wbase + x;
    if (i < n) {
        bptr[i + 1] = incl;
        cursor[i] = incl - v;
    }
    if (i == 0) bptr[0] = 0;
}

// ---------------------------------------------------------------------------
// R15: scatter RE-MERGED into gemm0 (R14 split proved overlap was worth
// ~40us: scatter alone 59us latency-bound at 0.5% VALU — it hides under the
// GEMM for free). Kept from R14: SINGLE-PASS scatter (edge arrays read once,
// 3125 scatter blocks not 12500) and the R13 clean A-only pipelined GEMM.
// ---------------------------------------------------------------------------
template<int BM, int BN, int K>
__global__ __launch_bounds__(256, 4) void gemm0_scatter_kernel(
        const float* __restrict__ Xg, const __hip_bfloat16* __restrict__ Wt,
        __hip_bfloat16* __restrict__ Ob, float* __restrict__ stats_out, int M,
        const int* __restrict__ rows, const int* __restrict__ cols,
        const float* __restrict__ vals, int* __restrict__ cursor,
        int2* __restrict__ csr_cv, int n, int gemmBlocks) {
    constexpr int BK  = 64;
    constexpr int LDK = 72;
    constexpr int WN  = BN / 64;
    __shared__ short As[BM * LDK];
    __shared__ short Bs[BN * LDK];
    int t = threadIdx.x;

    if ((int)blockIdx.x >= gemmBlocks) {   // ---- scatter path (single pass) ----
        int i = (blockIdx.x - gemmBlocks) * 256 + t;
        if (i >= n) return;
        int r = rows[i];
        int c = cols[i];
        int pos = atomicAdd(&cursor[r * NCB + c / CB_W], 1);
        csr_cv[pos] = make_int2(c, __float_as_int(vals[i]));
        return;
    }

    // ---- GEMM path (A-only pipelined reg-staging) ----
    if (blockIdx.x == 0)
        for (int z = t; z < NSLICE * SLICE_W; z += 256) stats_out[z] = 0.f;
    int lane = t & 63;
    int w = t >> 6;
    int wm = w / WN, wn = w % WN;
    int row0 = blockIdx.x * BM;
    int m0 = wm * 32, n0 = wn * 64;
    int l15 = lane & 15, quad = lane >> 4;

    f32x4 acc[2][4] = {};
    float4 pa[4];          // A prefetch: BM*16/256 = 4 float4 per thread

#define G0_LOADA(k0_) do {                                                     \
    _Pragma("unroll")                                                          \
    for (int u = 0; u < 4; ++u) {                                              \
        int idx = t + u * 256; int r = idx >> 4, c = idx & 15;                 \
        pa[u] = make_float4(0.f, 0.f, 0.f, 0.f);                               \
        if (row0 + r < M)                                                      \
            pa[u] = *(const float4*)(Xg + (size_t)(row0 + r) * K + (k0_) + c * 4); \
    }                                                                          \
} while (0)

#define G0_STOREA() do {                                                       \
    _Pragma("unroll")                                                          \
    for (int u = 0; u < 4; ++u) {                                              \
        int idx = t + u * 256; int r = idx >> 4, c = idx & 15;                 \
        __hip_bfloat16 o[4] = {__float2bfloat16(pa[u].x), __float2bfloat16(pa[u].y), \
                               __float2bfloat16(pa[u].z), __float2bfloat16(pa[u].w)}; \
        *(short4*)(As + r * LDK + c * 4) = *(short4*)o;                        \
    }                                                                          \
} while (0)

    G0_LOADA(0);
    for (int k0 = 0; k0 < K; k0 += BK) {
        #pragma unroll
        for (int idx = t; idx < BN * 8; idx += 256) {   // B inline (Wt is L2-hot)
            int r = idx >> 3, c = idx & 7;
            uint4 v = *(const uint4*)(Wt + (size_t)r * K + k0 + c * 8);
            *(uint4*)(Bs + r * LDK + c * 8) = v;
        }
        G0_STOREA();
        __syncthreads();
        if (k0 + BK < K) G0_LOADA(k0 + BK);   // next-step X loads in flight
        #pragma unroll
        for (int ks = 0; ks < 2; ++ks) {
            bf16x8 af[2], bfv[4];
            #pragma unroll
            for (int mt = 0; mt < 2; ++mt)
                af[mt] = *(const bf16x8*)(As + (m0 + mt * 16 + l15) * LDK + ks * 32 + quad * 8);
            #pragma unroll
            for (int nt = 0; nt < 4; ++nt)
                bfv[nt] = *(const bf16x8*)(Bs + (n0 + nt * 16 + l15) * LDK + ks * 32 + quad * 8);
            #pragma unroll
            for (int mt = 0; mt < 2; ++mt)
                #pragma unroll
                for (int nt = 0; nt < 4; ++nt)
                    acc[mt][nt] = __builtin_amdgcn_mfma_f32_16x16x32_bf16(
                        af[mt], bfv[nt], acc[mt][nt], 0, 0, 0);
        }
        __syncthreads();
    }
#undef G0_LOADA
#undef G0_STOREA
    #pragma unroll
    for (int mt = 0; mt < 2; ++mt) {
        #pragma unroll
        for (int reg = 0; reg < 4; ++reg) {
            int row = row0 + m0 + mt * 16 + quad * 4 + reg;
            if (row < M) {
                #pragma unroll
                for (int nt = 0; nt < 4; ++nt)
                    Ob[(size_t)row * BN + n0 + nt * 16 + l15] =
                        __float2bfloat16(acc[mt][nt][reg]);
            }
        }
    }
}

// ---------------------------------------------------------------------------
// Fused PN+GEMM (R13: A-only pipeline): k0=0 Bm/Xb loads issued BEFORE the
// stats prologue (hides slice-reduce under HBM latency); per-step A loads for
// k+1 issued after the first barrier of step k. Wt staged inline (L2-hot).
// ---------------------------------------------------------------------------
template<int BM, int BN, bool ADD_RESID, bool WRITE_X>
__global__ __launch_bounds__(256, 4) void mfma_gemm_pn(const __hip_bfloat16* __restrict__ Bm,
                                                    __hip_bfloat16* __restrict__ Xb,
                                                    const float* __restrict__ stats_in,
                                                    float* __restrict__ stats_out,
                                                    const __hip_bfloat16* __restrict__ Wt,
                                                    __hip_bfloat16* __restrict__ Ob, int M) {
    constexpr int K = 128, BK = 64, LDK = 72;
    constexpr int WN = BN / 64;
    constexpr int NA = BM * 8 / 256;   // A-stage uint4 per thread (2 or 4)
    __shared__ short As[BM * LDK];
    __shared__ short Bs[BN * LDK];
    __shared__ float smu[128];
    __shared__ float sred[128];
    __shared__ float ssq16[NSLICE];
    __shared__ float sscale;
    int t = threadIdx.x;
    int row0 = blockIdx.x * BM;

    uint4 pbm[NA], pxo[NA];

#define PN_LOADA(k0_) do {                                                     \
    _Pragma("unroll")                                                          \
    for (int u = 0; u < NA; ++u) {                                             \
        int idx = t + u * 256; int r = idx >> 3, c = idx & 7;                  \
        int gr = row0 + r;                                                     \
        bool ok = gr < M;                                                      \
        pbm[u] = make_uint4(0u, 0u, 0u, 0u);                                   \
        if (ok) pbm[u] = *(const uint4*)(Bm + (size_t)gr * 128 + (k0_) + c * 8); \
        if (ADD_RESID) {                                                       \
            pxo[u] = make_uint4(0u, 0u, 0u, 0u);                               \
            if (ok) pxo[u] = *(const uint4*)(Xb + (size_t)gr * 128 + (k0_) + c * 8); \
        }                                                                      \
    }                                                                          \
} while (0)

#define PN_STOREA(k0_) do {                                                    \
    _Pragma("unroll")                                                          \
    for (int u = 0; u < NA; ++u) {                                             \
        int idx = t + u * 256; int r = idx >> 3, c = idx & 7;                  \
        int gr = row0 + r; int k = (k0_) + c * 8;                              \
        unsigned short* bu = (unsigned short*)&pbm[u];                         \
        unsigned short* xu = (unsigned short*)&pxo[u];                         \
        __hip_bfloat16 o[8];                                                   \
        _Pragma("unroll")                                                      \
        for (int j = 0; j < 8; ++j) {                                          \
            float v = fmaxf((bf2f(bu[j]) - smu[k + j]) * sc, 0.f);             \
            if (ADD_RESID) v += bf2f(xu[j]);                                   \
            o[j] = __float2bfloat16(v);                                        \
        }                                                                      \
        *(uint4*)(As + r * LDK + c * 8) = *(uint4*)o;                          \
        if (WRITE_X && gr < M) *(uint4*)(Xb + (size_t)gr * 128 + k) = *(uint4*)o; \
    }                                                                          \
} while (0)

    PN_LOADA(0);   // in flight across the stats prologue

    if (stats_out && blockIdx.x == 0)
        for (int z = t; z < NSLICE * SLICE_W; z += 256) stats_out[z] = 0.f;
    if (t < NSLICE) ssq16[t] = stats_in[t * SLICE_W + 128];
    if (t < 128) {
        float cs = 0.f;
        #pragma unroll
        for (int s = 0; s < NSLICE; ++s) cs += stats_in[s * SLICE_W + t];
        float mu = cs * (1.0f / N_NODES);
        smu[t] = mu;
        sred[t] = mu * mu;
    }
    __syncthreads();
    for (int off = 64; off > 0; off >>= 1) {
        if (t < off) sred[t] += sred[t + off];
        __syncthreads();
    }
    if (t == 0) {
        float sq = 0.f;
        #pragma unroll
        for (int s = 0; s < NSLICE; ++s) sq += ssq16[s];
        float ms = sq * (1.0f / N_NODES) - sred[0];
        sscale = 1.0f / sqrtf(1e-6f + ms);   // PN_SCALE = 1
    }
    __syncthreads();
    float sc = sscale;

    int lane = t & 63;
    int w = t >> 6;
    int wm = w / WN, wn = w % WN;
    int m0 = wm * 32, n0 = wn * 64;
    int l15 = lane & 15, quad = lane >> 4;

    f32x4 acc[2][4] = {};

    for (int k0 = 0; k0 < K; k0 += BK) {
        #pragma unroll
        for (int idx = t; idx < BN * 8; idx += 256) {   // B inline (Wt is L2-hot)
            int r = idx >> 3, c = idx & 7;
            uint4 v = *(const uint4*)(Wt + (size_t)r * K + k0 + c * 8);
            *(uint4*)(Bs + r * LDK + c * 8) = v;
        }
        PN_STOREA(k0);
        __syncthreads();
        if (k0 + BK < K) PN_LOADA(k0 + BK);   // next-step A loads in flight
        #pragma unroll
        for (int ks = 0; ks < 2; ++ks) {
            bf16x8 af[2], bfv[4];
            #pragma unroll
            for (int mt = 0; mt < 2; ++mt)
                af[mt] = *(const bf16x8*)(As + (m0 + mt * 16 + l15) * LDK + ks * 32 + quad * 8);
            #pragma unroll
            for (int nt = 0; nt < 4; ++nt)
                bfv[nt] = *(const bf16x8*)(Bs + (n0 + nt * 16 + l15) * LDK + ks * 32 + quad * 8);
            #pragma unroll
            for (int mt = 0; mt < 2; ++mt)
                #pragma unroll
                for (int nt = 0; nt < 4; ++nt)
                    acc[mt][nt] = __builtin_amdgcn_mfma_f32_16x16x32_bf16(
                        af[mt], bfv[nt], acc[mt][nt], 0, 0, 0);
        }
        __syncthreads();
    }
#undef PN_LOADA
#undef PN_STOREA
    #pragma unroll
    for (int mt = 0; mt < 2; ++mt) {
        #pragma unroll
        for (int reg = 0; reg < 4; ++reg) {
            int row = row0 + m0 + mt * 16 + quad * 4 + reg;
            if (row < M) {
                #pragma unroll
                for (int nt = 0; nt < 4; ++nt)
                    Ob[(size_t)row * BN + n0 + nt * 16 + l15] =
                        __float2bfloat16(acc[mt][nt][reg]);
            }
        }
    }
}

// ---------------------------------------------------------------------------
// CSR SpMM, 128 feats (R11 body: one wave per row as 4 groups x 16 lanes,
// 16B/lane dwordx4 gathers, 16-edge main step. ALL hot-loop state in NAMED
// scalars. cv loads WAVE-UNIFORM (s_loads); group selects via 2-level cndmask.
// Fused PN stats epilogue: block LDS reduce -> 129 atomics into 1 of 16 slices.
// ---------------------------------------------------------------------------
#define SEL4(ca, cb, cc, cd, kk, vv) do {                                     \
    int kx_ = g1 ? (cb).x : (ca).x; int vx_ = g1 ? (cb).y : (ca).y;           \
    int ky_ = g1 ? (cd).x : (cc).x; int vy_ = g1 ? (cd).y : (cc).y;           \
    kk = g2 ? ky_ : kx_; vv = __int_as_float(g2 ? vy_ : vx_);                 \
} while (0)

#define FMA8(vv, hvv) do {                                                    \
    const unsigned short* hu_ = (const unsigned short*)&(hvv);                \
    acc0[0] = fmaf((vv), bf2f(hu_[0]), acc0[0]);                              \
    acc0[1] = fmaf((vv), bf2f(hu_[1]), acc0[1]);                              \
    acc0[2] = fmaf((vv), bf2f(hu_[2]), acc0[2]);                              \
    acc0[3] = fmaf((vv), bf2f(hu_[3]), acc0[3]);                              \
    acc1[0] = fmaf((vv), bf2f(hu_[4]), acc1[0]);                              \
    acc1[1] = fmaf((vv), bf2f(hu_[5]), acc1[1]);                              \
    acc1[2] = fmaf((vv), bf2f(hu_[6]), acc1[2]);                              \
    acc1[3] = fmaf((vv), bf2f(hu_[7]), acc1[3]);                              \
} while (0)

#define GATH(kk) (*(const uint4*)(Hu + (size_t)(kk) * 128 + sub * 8))

__global__ __launch_bounds__(256) void spmm_bf16_kernel(const __hip_bfloat16* __restrict__ H,
                                                        const int* __restrict__ bptr,
                                                        const int2* __restrict__ cv,
                                                        const float* __restrict__ bias,
                                                        __hip_bfloat16* __restrict__ Bm,
                                                        float* __restrict__ stats,
                                                        int nrows) {
    __shared__ float sm[129];
    int t = threadIdx.x;
    if (t < 129) sm[t] = 0.f;
    __syncthreads();
    int wid = (int)((blockIdx.x * blockDim.x + t) >> 6);
    wid = __builtin_amdgcn_readfirstlane(wid);
    int lane = t & 63;
    int g = lane >> 4;                  // edge group 0..3
    int sub = lane & 15;                // feats [8*sub .. 8*sub+7]
    bool g1 = (lane & 16) != 0;         // g&1
    bool g2 = (lane & 32) != 0;         // g&2
    const unsigned short* Hu = (const unsigned short*)H;   // row stride 128 ushort
    f32x4 acc0 = {0.f, 0.f, 0.f, 0.f};
    f32x4 acc1 = {0.f, 0.f, 0.f, 0.f};
    if (wid < nrows) {
        int s = bptr[wid * NCB];
        int e = bptr[wid * NCB + NCB];
        int i = s;
        for (; i + 15 < e; i += 16) {   // 16 edges: group g takes i+4j+g, j=0..3
            int2 c0  = cv[i + 0],  c1  = cv[i + 1],  c2  = cv[i + 2],  c3  = cv[i + 3];
            int2 c4  = cv[i + 4],  c5  = cv[i + 5],  c6  = cv[i + 6],  c7  = cv[i + 7];
            int2 c8  = cv[i + 8],  c9  = cv[i + 9],  c10 = cv[i + 10], c11 = cv[i + 11];
            int2 c12 = cv[i + 12], c13 = cv[i + 13], c14 = cv[i + 14], c15 = cv[i + 15];
            int k0, k1, k2, k3; float v0, v1, v2, v3;
            SEL4(c0,  c1,  c2,  c3,  k0, v0);
            SEL4(c4,  c5,  c6,  c7,  k1, v1);
            SEL4(c8,  c9,  c10, c11, k2, v2);
            SEL4(c12, c13, c14, c15, k3, v3);
            uint4 h0 = GATH(k0);
            uint4 h1 = GATH(k1);
            uint4 h2 = GATH(k2);
            uint4 h3 = GATH(k3);
            FMA8(v0, h0);
            FMA8(v1, h1);
            FMA8(v2, h2);
            FMA8(v3, h3);
        }
        if (i + 7 < e) {                // 8 edges: group g takes i+4j+g, j=0..1
            int2 c0 = cv[i + 0], c1 = cv[i + 1], c2 = cv[i + 2], c3 = cv[i + 3];
            int2 c4 = cv[i + 4], c5 = cv[i + 5], c6 = cv[i + 6], c7 = cv[i + 7];
            int k0, k1; float v0, v1;
            SEL4(c0, c1, c2, c3, k0, v0);
            SEL4(c4, c5, c6, c7, k1, v1);
            uint4 h0 = GATH(k0);
            uint4 h1 = GATH(k1);
            FMA8(v0, h0);
            FMA8(v1, h1);
            i += 8;
        }
        if (i + 3 < e) {                // 4 edges: group g takes i+g
            int2 c0 = cv[i + 0], c1 = cv[i + 1], c2 = cv[i + 2], c3 = cv[i + 3];
            int k0; float v0;
            SEL4(c0, c1, c2, c3, k0, v0);
            uint4 h0 = GATH(k0);
            FMA8(v0, h0);
            i += 4;
        }
        int rr = e - i;                 // 0..3 partial: groups g<rr, one v-load
        if (g < rr) {
            int2 cc = cv[i + g];
            float v0 = __int_as_float(cc.y);
            uint4 h0 = GATH(cc.x);
            FMA8(v0, h0);
        }
    }
    // combine the 4 edge groups
    #pragma unroll
    for (int q = 0; q < 4; ++q) {
        acc0[q] += __shfl_xor(acc0[q], 16);
        acc0[q] += __shfl_xor(acc0[q], 32);
        acc1[q] += __shfl_xor(acc1[q], 16);
        acc1[q] += __shfl_xor(acc1[q], 32);
    }
    if (wid < nrows && lane < 16) {
        float4 ba = *(const float4*)(bias + 8 * sub);
        float4 bb = *(const float4*)(bias + 8 * sub + 4);
        float v0 = acc0[0] + ba.x, v1 = acc0[1] + ba.y;
        float v2 = acc0[2] + ba.z, v3 = acc0[3] + ba.w;
        float v4 = acc1[0] + bb.x, v5 = acc1[1] + bb.y;
        float v6 = acc1[2] + bb.z, v7 = acc1[3] + bb.w;
        __hip_bfloat16 o[8] = {__float2bfloat16(v0), __float2bfloat16(v1),
                               __float2bfloat16(v2), __float2bfloat16(v3),
                               __float2bfloat16(v4), __float2bfloat16(v5),
                               __float2bfloat16(v6), __float2bfloat16(v7)};
        *(uint4*)(Bm + (size_t)wid * 128 + 8 * sub) = *(uint4*)o;
        // PN stats: lane owns cols 8sub..8sub+7 exclusively within its wave
        atomicAdd(&sm[8 * sub + 0], v0);
        atomicAdd(&sm[8 * sub + 1], v1);
        atomicAdd(&sm[8 * sub + 2], v2);
        atomicAdd(&sm[8 * sub + 3], v3);
        atomicAdd(&sm[8 * sub + 4], v4);
        atomicAdd(&sm[8 * sub + 5], v5);
        atomicAdd(&sm[8 * sub + 6], v6);
        atomicAdd(&sm[8 * sub + 7], v7);
        float sq = v0 * v0 + v1 * v1 + v2 * v2 + v3 * v3
                 + v4 * v4 + v5 * v5 + v6 * v6 + v7 * v7;
        #pragma unroll
        for (int off = 8; off > 0; off >>= 1) sq += __shfl_down(sq, off, 16);
        if (sub == 0) atomicAdd(&sm[128], sq);
    }
    __syncthreads();
    if (t < 129)
        atomicAdd(&stats[(blockIdx.x & (NSLICE - 1)) * SLICE_W + t], sm[t]);
}

// ---------------------------------------------------------------------------
// Final SpMM, 64-wide G (cols 40..63 zero) — R8 body (wave-uniform cv loads)
// ---------------------------------------------------------------------------
__global__ __launch_bounds__(256) void spmm_out_kernel(const __hip_bfloat16* __restrict__ G,
                                                       const int* __restrict__ bptr,
                                                       const int2* __restrict__ cv,
                                                       const float* __restrict__ bias,
                                                       float* __restrict__ out, int nrows) {
    int wid = (int)((blockIdx.x * blockDim.x + threadIdx.x) >> 6);
    wid = __builtin_amdgcn_readfirstlane(wid);
    int lane = threadIdx.x & 63;
    int h = lane >> 5;
    int sub = lane & 31;                    // feats {2sub, 2sub+1}
    if (wid >= nrows) return;
    int s = bptr[wid * NCB];
    int e = bptr[wid * NCB + NCB];
    const __hip_bfloat162* G2 = (const __hip_bfloat162*)G;   // row stride 32
    float a0 = 0.f, a1 = 0.f;
    int i = s;
    for (; i + 7 < e; i += 8) {
        int2 c0 = cv[i],     c1 = cv[i + 1], c2 = cv[i + 2], c3 = cv[i + 3];
        int2 c4 = cv[i + 4], c5 = cv[i + 5], c6 = cv[i + 6], c7 = cv[i + 7];
        int   ka = h ? c4.x : c0.x;  float va = __int_as_float(h ? c4.y : c0.y);
        int   kb = h ? c5.x : c1.x;  float vb = __int_as_float(h ? c5.y : c1.y);
        int   kc = h ? c6.x : c2.x;  float vc = __int_as_float(h ? c6.y : c2.y);
        int   kd = h ? c7.x : c3.x;  float vd = __int_as_float(h ? c7.y : c3.y);
        __hip_bfloat162 ga = G2[(size_t)ka * 32 + sub];
        __hip_bfloat162 gb = G2[(size_t)kb * 32 + sub];
        __hip_bfloat162 gc = G2[(size_t)kc * 32 + sub];
        __hip_bfloat162 gd = G2[(size_t)kd * 32 + sub];
        a0 = fmaf(va, __bfloat162float(ga.x), a0); a1 = fmaf(va, __bfloat162float(ga.y), a1);
        a0 = fmaf(vb, __bfloat162float(gb.x), a0); a1 = fmaf(vb, __bfloat162float(gb.y), a1);
        a0 = fmaf(vc, __bfloat162float(gc.x), a0); a1 = fmaf(vc, __bfloat162float(gc.y), a1);
        a0 = fmaf(vd, __bfloat162float(gd.x), a0); a1 = fmaf(vd, __bfloat162float(gd.y), a1);
    }
    for (; i + 3 < e; i += 4) {
        int2 c0 = cv[i], c1 = cv[i + 1], c2 = cv[i + 2], c3 = cv[i + 3];
        int   ka = h ? c2.x : c0.x;  float va = __int_as_float(h ? c2.y : c0.y);
        int   kb = h ? c3.x : c1.x;  float vb = __int_as_float(h ? c3.y : c1.y);
        __hip_bfloat162 ga = G2[(size_t)ka * 32 + sub];
        __hip_bfloat162 gb = G2[(size_t)kb * 32 + sub];
        a0 = fmaf(va, __bfloat162float(ga.x), a0); a1 = fmaf(va, __bfloat162float(ga.y), a1);
        a0 = fmaf(vb, __bfloat162float(gb.x), a0); a1 = fmaf(vb, __bfloat162float(gb.y), a1);
    }
    for (; i < e; ++i) {
        int2 c = cv[i];
        if (h == 0) {
            float v = __int_as_float(c.y);
            __hip_bfloat162 g = G2[(size_t)c.x * 32 + sub];
            a0 = fmaf(v, __bfloat162float(g.x), a0);
            a1 = fmaf(v, __bfloat162float(g.y), a1);
        }
    }
    a0 += __shfl_xor(a0, 32);
    a1 += __shfl_xor(a1, 32);
    if (h == 0 && sub < NCLASS / 2) {
        float2 b2 = *(const float2*)(bias + 2 * sub);
        float2 o = make_float2(a0 + b2.x, a1 + b2.y);
        *(float2*)(out + (size_t)wid * NCLASS + 2 * sub) = o;
    }
}

// ---------------------------------------------------------------------------
extern "C" void kernel_launch(void* const* d_in, const int* in_sizes, int n_in,
                              void* d_out, int out_size, void* d_ws, size_t ws_size,
                              hipStream_t stream) {
    const float* x        = (const float*)d_in[0];
    const int*   edge_row = (const int*)  d_in[1];
    const int*   edge_col = (const int*)  d_in[2];
    const float* edge_val = (const float*)d_in[3];
    const float* W0 = (const float*)d_in[4];
    const float* b0 = (const float*)d_in[5];
    const float* W1 = (const float*)d_in[6];
    const float* b1 = (const float*)d_in[7];
    const float* W2 = (const float*)d_in[8];
    const float* b2 = (const float*)d_in[9];
    const float* W_out = (const float*)d_in[10];
    const float* b_out = (const float*)d_in[11];
    float* out = (float*)d_out;

    const size_t NH = (size_t)N_NODES * NHID;   // 6,400,000

    char* p = (char*)d_ws;
    __hip_bfloat16* Xb   = (__hip_bfloat16*)p;  p += NH * 2;
    __hip_bfloat16* A_bf = (__hip_bfloat16*)p;  p += NH * 2;
    __hip_bfloat16* Bm   = (__hip_bfloat16*)p;  p += NH * 2;
    __hip_bfloat16* Wt0 = (__hip_bfloat16*)p;   p += (size_t)128 * 512 * 2;
    __hip_bfloat16* Wt1 = (__hip_bfloat16*)p;   p += (size_t)128 * 128 * 2;
    __hip_bfloat16* Wt2 = (__hip_bfloat16*)p;   p += (size_t)128 * 128 * 2;
    __hip_bfloat16* Wot = (__hip_bfloat16*)p;   p += (size_t)64 * 128 * 2;
    float* statsA   = (float*)p;                p += (size_t)NSLICE * SLICE_W * 4;
    float* statsB   = (float*)p;                p += (size_t)NSLICE * SLICE_W * 4;
    int* cnt      = (int*)p;                    p += (size_t)NCNT * 4;
    int* bptr     = (int*)p;                    p += (size_t)(NCNT + 1) * 4 + 4; // int2 align
    int* cursor   = (int*)p;                    p += (size_t)NCNT * 4;
    int* bsum     = (int*)p;                    p += (size_t)SCAN_BLOCKS * 4 + 4;
    int2* csr_cv  = (int2*)p;                   p += (size_t)N_EDGES * 8;

    const int EB = (N_EDGES + 255) / 256;         // 3125 blocks
    const int SPMM_GRID = (N_NODES + 3) / 4;      // 12500 (4 waves/block)
    const int GEMM0_BLOCKS = (N_NODES + 63) / 64; // 782

    // --- CSR build + weight conversion (merged/overlapped) ---
    hipMemsetAsync(cnt, 0, NCNT * sizeof(int), stream);
    wt_hist_kernel<<<WT_BLOCKS + EB, 256, 0, stream>>>(
        W0, W1, W2, W_out, Wt0, Wt1, Wt2, Wot, edge_row, edge_col, cnt, N_EDGES);
    scan_p1_kernel<<<SCAN_BLOCKS, 1024, 0, stream>>>(cnt, bsum, NCNT);
    scan_p2_kernel<<<1, 512, 0, stream>>>(bsum, SCAN_BLOCKS);
    scan_p3_kernel<<<SCAN_BLOCKS, 1024, 0, stream>>>(cnt, bsum, bptr, cursor, NCNT);

    // --- layer 0 GEMM + single-pass scatter, one launch (overlap) ---
    gemm0_scatter_kernel<64, 128, 512><<<GEMM0_BLOCKS + EB, 256, 0, stream>>>(
        x, Wt0, A_bf, statsA, N_NODES,
        edge_row, edge_col, edge_val, cursor, csr_cv, N_EDGES, GEMM0_BLOCKS);
    spmm_bf16_kernel<<<SPMM_GRID, 256, 0, stream>>>(A_bf, bptr, csr_cv, b0, Bm,
                                                    statsA, N_NODES);

    // --- layer 1: PN(statsA)+GEMM (writes Xb=x1, zeros statsB) -> SpMM(statsB)
    mfma_gemm_pn<64, 128, false, true><<<GEMM0_BLOCKS, 256, 0, stream>>>(
        Bm, Xb, statsA, statsB, Wt1, A_bf, N_NODES);
    spmm_bf16_kernel<<<SPMM_GRID, 256, 0, stream>>>(A_bf, bptr, csr_cv, b1, Bm,
                                                    statsB, N_NODES);

    // --- layer 2: PN(statsB)+resid+GEMM (Xb=x2, zeros statsA) -> SpMM(statsA)
    mfma_gemm_pn<64, 128, true, true><<<GEMM0_BLOCKS, 256, 0, stream>>>(
        Bm, Xb, statsB, statsA, Wt2, A_bf, N_NODES);
    spmm_bf16_kernel<<<SPMM_GRID, 256, 0, stream>>>(A_bf, bptr, csr_cv, b2, Bm,
                                                    statsA, N_NODES);

    // --- head: PN(statsA)+resid(x2), x3 never materialized; Gp = x3 @ Wot^T ---
    mfma_gemm_pn<128, 64, true, false><<<(N_NODES + 127) / 128, 256, 0, stream>>>(
        Bm, Xb, statsA, nullptr, Wot, A_bf, N_NODES);
    spmm_out_kernel<<<(N_NODES + 3) / 4, 256, 0, stream>>>(A_bf, bptr, csr_cv, b_out,
                                                           out, N_NODES);
}